// Round 4
// baseline (461.456 us; speedup 1.0000x reference)
//
#include <hip/hip_runtime.h>

// PEG_Shift: depthwise 3x3 conv (stride 1, pad 1, groups=C), power-of-two weights,
// 16-bit fixed-point activations/bias. x: (32,384,56,56) f32.
//
// v5 = v4 with the segment-mapping bug fixed (r0 = 0/19/38; v4's formula gave 37
// and left output row 55 unwritten). Zero-LDS register streaming:
//   - 3 row-segments per column (19/19/18) -> 2016 blocks, ALL co-resident at
//     8 waves/SIMD (__launch_bounds__(256,8)) ~= 98% wave-slot occupancy
//   - 2-deep raw-row prefetch (rows r+2 and r+3 in flight)
//   - nontemporal float4 stores: write-once output stops evicting input from L3

#define DW_C   384
#define DW_H   56
#define DW_W   56
#define DW_HW  3136
#define NW4    14

typedef float v4f __attribute__((ext_vector_type(4)));

__device__ __forceinline__ float qfix(float v) {
    // floor(v * 2^16) * 2^-16, clip [-2^15, 2^15-1] — exact in fp32
    v = floorf(v * 65536.0f) * (1.0f / 65536.0f);
    return fminf(fmaxf(v, -32768.0f), 32767.0f);   // v_med3_f32
}

struct Row { float l, a, b, c, d, r; };

// ---- pre-kernel: quantize 3456 weights (power of two) + 384 biases into d_ws ----
__global__ __launch_bounds__(256) void quant_wb(
    const float* __restrict__ wgt, const float* __restrict__ bias,
    float* __restrict__ wq, float* __restrict__ bq)
{
    int i = blockIdx.x * 256 + threadIdx.x;
    if (i < DW_C * 9) {
        float wv = wgt[i];
        float aw = fabsf(wv);
        float cw = fminf(fmaxf(aw, 6.103515625e-05f /*2^-14*/), 1.0f);
        float q  = exp2f(rintf(log2f(cw)));        // rint = round-half-even (jnp.round)
        wq[i] = (wv > 0.0f) ? q : ((wv < 0.0f) ? -q : 0.0f);
    }
    if (i < DW_C) bq[i] = qfix(bias[i]);
}

template<bool PRE>
__global__ __launch_bounds__(256, 8) void peg_shift_stream(
    const float* __restrict__ x, const float* __restrict__ wgt,
    const float* __restrict__ bias, float* __restrict__ out,
    const float* __restrict__ wsq, const float* __restrict__ wsb,
    int ntask)
{
    const int task = blockIdx.x * 256 + threadIdx.x;
    if (task >= ntask) return;

    // task -> (plane, seg, w4). 42 strips/plane: 3 row-segments x 14 col-strips.
    const int plane = task / 42;
    const int t42   = task - plane * 42;
    const int seg   = t42 / NW4;                  // 0,1,2
    const int w4    = t42 - seg * NW4;
    const int c     = plane % DW_C;
    const int r0    = seg * 19;                   // 0, 19, 38
    const int n     = (seg == 2) ? 18 : 19;       // rows: 0-18, 19-37, 38-55
    const int rlim  = min(r0 + n + 1, DW_H);      // last row actually needed + 1

    const bool hl = (w4 > 0);
    const bool hr = (w4 < NW4 - 1);

    // ---- per-channel quantized weights + bias ----
    float ww[9];
    float bqv;
    if (PRE) {
        const float* wp = wsq + c * 9;
#pragma unroll
        for (int t = 0; t < 9; ++t) ww[t] = wp[t];
        bqv = wsb[c];
    } else {
        const float* wp = wgt + c * 9;
#pragma unroll
        for (int t = 0; t < 9; ++t) {
            float wv = wp[t];
            float aw = fabsf(wv);
            float cw = fminf(fmaxf(aw, 6.103515625e-05f), 1.0f);
            float q  = exp2f(rintf(log2f(cw)));
            ww[t] = (wv > 0.0f) ? q : ((wv < 0.0f) ? -q : 0.0f);
        }
        bqv = qfix(bias[c]);
    }

    const float* xb = x + (size_t)plane * DW_HW + w4 * 4;

    // raw (unquantized) row load, zero outside [0, rlim)
    auto loadraw = [&](int rr, float4& m, float& lv, float& rv) {
        m.x = m.y = m.z = m.w = 0.0f; lv = 0.0f; rv = 0.0f;
        if (rr >= 0 && rr < rlim) {
            const float* p = xb + rr * DW_W;
            m = *(const float4*)p;                 // aligned 16B
            if (hl) lv = p[-1];                    // L1 hit (neighbor lane's line)
            if (hr) rv = p[4];
        }
    };
    auto quant = [&](const float4& m, float lv, float rv) -> Row {
        Row q;
        q.l = qfix(lv);  q.a = qfix(m.x); q.b = qfix(m.y);
        q.c = qfix(m.z); q.d = qfix(m.w); q.r = qfix(rv);
        return q;
    };

    // ---- prologue: window rows r0-1..r0+1 quantized, row r0+2 raw in flight ----
    float4 m0, m1, m2, mP, mQ;
    float  l0, r0v, l1, r1v, l2, r2v, lP, rP, lQ, rQ;
    loadraw(r0 - 1, m0, l0, r0v);
    loadraw(r0,     m1, l1, r1v);
    loadraw(r0 + 1, m2, l2, r2v);
    loadraw(r0 + 2, mP, lP, rP);
    Row A = quant(m0, l0, r0v);
    Row B = quant(m1, l1, r1v);
    Row C = quant(m2, l2, r2v);

    float* ob = out + (size_t)plane * DW_HW + r0 * DW_W + w4 * 4;

    for (int i = 0; i < n; ++i) {
        // ---- issue row r0+i+3 (2-deep prefetch: P=r+2 already in flight) ----
        loadraw(r0 + i + 3, mQ, lQ, rQ);

        // ---- compute output row r0+i from A,B,C ----
        float o0 = bqv, o1 = bqv, o2 = bqv, o3 = bqv;
        o0 = fmaf(A.l, ww[0], fmaf(A.a, ww[1], fmaf(A.b, ww[2], o0)));
        o1 = fmaf(A.a, ww[0], fmaf(A.b, ww[1], fmaf(A.c, ww[2], o1)));
        o2 = fmaf(A.b, ww[0], fmaf(A.c, ww[1], fmaf(A.d, ww[2], o2)));
        o3 = fmaf(A.c, ww[0], fmaf(A.d, ww[1], fmaf(A.r, ww[2], o3)));
        o0 = fmaf(B.l, ww[3], fmaf(B.a, ww[4], fmaf(B.b, ww[5], o0)));
        o1 = fmaf(B.a, ww[3], fmaf(B.b, ww[4], fmaf(B.c, ww[5], o1)));
        o2 = fmaf(B.b, ww[3], fmaf(B.c, ww[4], fmaf(B.d, ww[5], o2)));
        o3 = fmaf(B.c, ww[3], fmaf(B.d, ww[4], fmaf(B.r, ww[5], o3)));
        o0 = fmaf(C.l, ww[6], fmaf(C.a, ww[7], fmaf(C.b, ww[8], o0)));
        o1 = fmaf(C.a, ww[6], fmaf(C.b, ww[7], fmaf(C.c, ww[8], o1)));
        o2 = fmaf(C.b, ww[6], fmaf(C.c, ww[7], fmaf(C.d, ww[8], o2)));
        o3 = fmaf(C.c, ww[6], fmaf(C.d, ww[7], fmaf(C.r, ww[8], o3)));

        v4f ov; ov.x = o0; ov.y = o1; ov.z = o2; ov.w = o3;
        __builtin_nontemporal_store(ov, (v4f*)ob);   // write-once: don't pollute L3
        ob += DW_W;

        // ---- rotate window: quantize P, promote Q ----
        A = B; B = C;
        C = quant(mP, lP, rP);
        mP = mQ; lP = lQ; rP = rQ;
    }
}

extern "C" void kernel_launch(void* const* d_in, const int* in_sizes, int n_in,
                              void* d_out, int out_size, void* d_ws, size_t ws_size,
                              hipStream_t stream) {
    const float* x = (const float*)d_in[0];
    const float* w = (const float*)d_in[1];
    const float* b = (const float*)d_in[2];
    float* out = (float*)d_out;

    int planes  = in_sizes[0] / DW_HW;          // 32*384 = 12288
    int tasks   = planes * 42;                  // 516096
    int nblocks = (tasks + 255) / 256;          // 2016 -> all co-resident

    size_t need = (size_t)(DW_C * 9 + DW_C) * sizeof(float);
    if (d_ws && ws_size >= need) {
        float* wq = (float*)d_ws;
        float* bq = wq + DW_C * 9;
        quant_wb<<<(DW_C * 9 + 255) / 256, 256, 0, stream>>>(w, b, wq, bq);
        peg_shift_stream<true><<<nblocks, 256, 0, stream>>>(x, w, b, out, wq, bq, tasks);
    } else {
        peg_shift_stream<false><<<nblocks, 256, 0, stream>>>(x, w, b, out, nullptr, nullptr, tasks);
    }
}

// Round 6
// 330.477 us; speedup vs baseline: 1.3963x; 1.3963x over previous
//
#include <hip/hip_runtime.h>

// PEG_Shift: depthwise 3x3 conv (stride 1, pad 1, groups=C), power-of-two weights,
// 16-bit fixed-point activations/bias. x: (32,384,56,56) f32.
//
// v6 = v5 with PLAIN stores. v5's __builtin_nontemporal_store bypassed L2
// write-combining: each 16B partial-line store caused a 64B line RMW at HBM
// (FETCH 84->705 MB measured). Regular float4 stores merge in L2.
// Structure: zero-LDS register streaming, 3 row-segments (19/19/18) -> 2016
// blocks all co-resident at 8 waves/SIMD (VGPR=32), 2-deep raw-row prefetch.
// (Resubmission: round-5 bench died on container acquisition, kernel unmeasured.)

#define DW_C   384
#define DW_H   56
#define DW_W   56
#define DW_HW  3136
#define NW4    14

__device__ __forceinline__ float qfix(float v) {
    // floor(v * 2^16) * 2^-16, clip [-2^15, 2^15-1] — exact in fp32
    v = floorf(v * 65536.0f) * (1.0f / 65536.0f);
    return fminf(fmaxf(v, -32768.0f), 32767.0f);   // v_med3_f32
}

struct Row { float l, a, b, c, d, r; };

// ---- pre-kernel: quantize 3456 weights (power of two) + 384 biases into d_ws ----
__global__ __launch_bounds__(256) void quant_wb(
    const float* __restrict__ wgt, const float* __restrict__ bias,
    float* __restrict__ wq, float* __restrict__ bq)
{
    int i = blockIdx.x * 256 + threadIdx.x;
    if (i < DW_C * 9) {
        float wv = wgt[i];
        float aw = fabsf(wv);
        float cw = fminf(fmaxf(aw, 6.103515625e-05f /*2^-14*/), 1.0f);
        float q  = exp2f(rintf(log2f(cw)));        // rint = round-half-even (jnp.round)
        wq[i] = (wv > 0.0f) ? q : ((wv < 0.0f) ? -q : 0.0f);
    }
    if (i < DW_C) bq[i] = qfix(bias[i]);
}

template<bool PRE>
__global__ __launch_bounds__(256, 8) void peg_shift_stream(
    const float* __restrict__ x, const float* __restrict__ wgt,
    const float* __restrict__ bias, float* __restrict__ out,
    const float* __restrict__ wsq, const float* __restrict__ wsb,
    int ntask)
{
    const int task = blockIdx.x * 256 + threadIdx.x;
    if (task >= ntask) return;

    // task -> (plane, seg, w4). 42 strips/plane: 3 row-segments x 14 col-strips.
    const int plane = task / 42;
    const int t42   = task - plane * 42;
    const int seg   = t42 / NW4;                  // 0,1,2
    const int w4    = t42 - seg * NW4;
    const int c     = plane % DW_C;
    const int r0    = seg * 19;                   // 0, 19, 38
    const int n     = (seg == 2) ? 18 : 19;       // rows: 0-18, 19-37, 38-55
    const int rlim  = min(r0 + n + 1, DW_H);      // last row actually needed + 1

    const bool hl = (w4 > 0);
    const bool hr = (w4 < NW4 - 1);

    // ---- per-channel quantized weights + bias ----
    float ww[9];
    float bqv;
    if (PRE) {
        const float* wp = wsq + c * 9;
#pragma unroll
        for (int t = 0; t < 9; ++t) ww[t] = wp[t];
        bqv = wsb[c];
    } else {
        const float* wp = wgt + c * 9;
#pragma unroll
        for (int t = 0; t < 9; ++t) {
            float wv = wp[t];
            float aw = fabsf(wv);
            float cw = fminf(fmaxf(aw, 6.103515625e-05f), 1.0f);
            float q  = exp2f(rintf(log2f(cw)));
            ww[t] = (wv > 0.0f) ? q : ((wv < 0.0f) ? -q : 0.0f);
        }
        bqv = qfix(bias[c]);
    }

    const float* xb = x + (size_t)plane * DW_HW + w4 * 4;

    // raw (unquantized) row load, zero outside [0, rlim)
    auto loadraw = [&](int rr, float4& m, float& lv, float& rv) {
        m.x = m.y = m.z = m.w = 0.0f; lv = 0.0f; rv = 0.0f;
        if (rr >= 0 && rr < rlim) {
            const float* p = xb + rr * DW_W;
            m = *(const float4*)p;                 // aligned 16B
            if (hl) lv = p[-1];                    // L1 hit (neighbor lane's line)
            if (hr) rv = p[4];
        }
    };
    auto quant = [&](const float4& m, float lv, float rv) -> Row {
        Row q;
        q.l = qfix(lv);  q.a = qfix(m.x); q.b = qfix(m.y);
        q.c = qfix(m.z); q.d = qfix(m.w); q.r = qfix(rv);
        return q;
    };

    // ---- prologue: window rows r0-1..r0+1 quantized, row r0+2 raw in flight ----
    float4 m0, m1, m2, mP, mQ;
    float  l0, r0v, l1, r1v, l2, r2v, lP, rP, lQ, rQ;
    loadraw(r0 - 1, m0, l0, r0v);
    loadraw(r0,     m1, l1, r1v);
    loadraw(r0 + 1, m2, l2, r2v);
    loadraw(r0 + 2, mP, lP, rP);
    Row A = quant(m0, l0, r0v);
    Row B = quant(m1, l1, r1v);
    Row C = quant(m2, l2, r2v);

    float* ob = out + (size_t)plane * DW_HW + r0 * DW_W + w4 * 4;

    for (int i = 0; i < n; ++i) {
        // ---- issue row r0+i+3 (2-deep prefetch: P=r+2 already in flight) ----
        loadraw(r0 + i + 3, mQ, lQ, rQ);

        // ---- compute output row r0+i from A,B,C ----
        float o0 = bqv, o1 = bqv, o2 = bqv, o3 = bqv;
        o0 = fmaf(A.l, ww[0], fmaf(A.a, ww[1], fmaf(A.b, ww[2], o0)));
        o1 = fmaf(A.a, ww[0], fmaf(A.b, ww[1], fmaf(A.c, ww[2], o1)));
        o2 = fmaf(A.b, ww[0], fmaf(A.c, ww[1], fmaf(A.d, ww[2], o2)));
        o3 = fmaf(A.c, ww[0], fmaf(A.d, ww[1], fmaf(A.r, ww[2], o3)));
        o0 = fmaf(B.l, ww[3], fmaf(B.a, ww[4], fmaf(B.b, ww[5], o0)));
        o1 = fmaf(B.a, ww[3], fmaf(B.b, ww[4], fmaf(B.c, ww[5], o1)));
        o2 = fmaf(B.b, ww[3], fmaf(B.c, ww[4], fmaf(B.d, ww[5], o2)));
        o3 = fmaf(B.c, ww[3], fmaf(B.d, ww[4], fmaf(B.r, ww[5], o3)));
        o0 = fmaf(C.l, ww[6], fmaf(C.a, ww[7], fmaf(C.b, ww[8], o0)));
        o1 = fmaf(C.a, ww[6], fmaf(C.b, ww[7], fmaf(C.c, ww[8], o1)));
        o2 = fmaf(C.b, ww[6], fmaf(C.c, ww[7], fmaf(C.d, ww[8], o2)));
        o3 = fmaf(C.c, ww[6], fmaf(C.d, ww[7], fmaf(C.r, ww[8], o3)));

        float4 ov; ov.x = o0; ov.y = o1; ov.z = o2; ov.w = o3;
        *(float4*)ob = ov;                         // plain store: L2 write-combines
        ob += DW_W;

        // ---- rotate window: quantize P, promote Q ----
        A = B; B = C;
        C = quant(mP, lP, rP);
        mP = mQ; lP = lQ; rP = rQ;
    }
}

extern "C" void kernel_launch(void* const* d_in, const int* in_sizes, int n_in,
                              void* d_out, int out_size, void* d_ws, size_t ws_size,
                              hipStream_t stream) {
    const float* x = (const float*)d_in[0];
    const float* w = (const float*)d_in[1];
    const float* b = (const float*)d_in[2];
    float* out = (float*)d_out;

    int planes  = in_sizes[0] / DW_HW;          // 32*384 = 12288
    int tasks   = planes * 42;                  // 516096
    int nblocks = (tasks + 255) / 256;          // 2016 -> all co-resident

    size_t need = (size_t)(DW_C * 9 + DW_C) * sizeof(float);
    if (d_ws && ws_size >= need) {
        float* wq = (float*)d_ws;
        float* bq = wq + DW_C * 9;
        quant_wb<<<(DW_C * 9 + 255) / 256, 256, 0, stream>>>(w, b, wq, bq);
        peg_shift_stream<true><<<nblocks, 256, 0, stream>>>(x, w, b, out, wq, bq, tasks);
    } else {
        peg_shift_stream<false><<<nblocks, 256, 0, stream>>>(x, w, b, out, nullptr, nullptr, tasks);
    }
}

// Round 8
// 281.568 us; speedup vs baseline: 1.6389x; 1.1737x over previous
//
#include <hip/hip_runtime.h>

// PEG_Shift: depthwise 3x3 conv (stride 1, pad 1, groups=C), power-of-two weights,
// 16-bit fixed-point activations/bias. x: (32,384,56,56) f32.
//
// v7: pipelined half-plane LDS kernel (v1 structure + T14 overlap).
//   Evidence: v1 (96us) had VALU 38us + LDS 23us + HBM 47us ~= 96us -> pipes
//   serialized by the stage->barrier->compute phase structure. v7 keeps loads
//   in flight DURING compute:
//   - chunk = half plane (28 out rows) staged as 30 rows incl. zero halos
//     -> unconditional 3-row compute, LDS 2 x 6.72 KB = 13.4 KB -> 8 blocks/CU
//   - 2048 blocks (8/CU exact), 6 planes = 12 chunks per block
//   - per chunk: issue next chunk's global loads -> compute current from LDS
//     -> qfix+ds_write next -> barrier  (one barrier per chunk)
//   - weights/bias pre-quantized into d_ws (scalar loads, no transcendentals)
// (Resubmission: round-7 bench died on container acquisition, kernel unmeasured.)

#define DW_C    384
#define DW_H    56
#define DW_W    56
#define DW_HW   3136
#define NW4     14
#define PPB     6                 // planes per block -> 12288/6 = 2048 blocks
#define CHUNKS  (PPB * 2)
#define SROWS   30                // 28 output rows + 2 halo rows
#define SFLOATS (SROWS * DW_W)    // 1680 floats = 6720 B per buffer
#define SIDX_N  (SROWS * NW4)     // 420 float4 staging slots
#define OIDX_N  (28 * NW4)        // 392 float4 outputs per chunk

__device__ __forceinline__ float qfix(float v) {
    // floor(v * 2^16) * 2^-16, clip [-2^15, 2^15-1] — exact in fp32
    v = floorf(v * 65536.0f) * (1.0f / 65536.0f);
    return fminf(fmaxf(v, -32768.0f), 32767.0f);   // v_med3_f32
}

__device__ __forceinline__ float4 qfix4(float4 v) {
    v.x = qfix(v.x); v.y = qfix(v.y); v.z = qfix(v.z); v.w = qfix(v.w);
    return v;
}

// ---- pre-kernel: quantize 3456 weights (power of two) + 384 biases into d_ws ----
__global__ __launch_bounds__(256) void quant_wb(
    const float* __restrict__ wgt, const float* __restrict__ bias,
    float* __restrict__ wq, float* __restrict__ bq)
{
    int i = blockIdx.x * 256 + threadIdx.x;
    if (i < DW_C * 9) {
        float wv = wgt[i];
        float aw = fabsf(wv);
        float cw = fminf(fmaxf(aw, 6.103515625e-05f /*2^-14*/), 1.0f);
        float q  = exp2f(rintf(log2f(cw)));        // rint = round-half-even (jnp.round)
        wq[i] = (wv > 0.0f) ? q : ((wv < 0.0f) ? -q : 0.0f);
    }
    if (i < DW_C) bq[i] = qfix(bias[i]);
}

template<bool PRE>
__global__ __launch_bounds__(256, 8) void peg_shift_pipe(
    const float* __restrict__ x, const float* __restrict__ wgt,
    const float* __restrict__ bias, float* __restrict__ out,
    const float* __restrict__ wsq, const float* __restrict__ wsb)
{
    __shared__ float s[2][SFLOATS];

    const int tid = threadIdx.x;
    const int p0  = blockIdx.x * PPB;

    // ---- chunk-invariant index precompute ----
    // staging: sidx = tid (always < 420) and tid+256 (if < 420)
    const int  s0r = tid / NW4, s0c = tid - s0r * NW4;
    const int  s1i = tid + 256;
    const bool st1 = (s1i < SIDX_N);
    const int  s1r = s1i / NW4, s1c = s1i - s1r * NW4;
    // compute: oidx = tid (always < 392... tid<256) and tid+256 (if < 392)
    // o0r,o0c == s0r,s0c (same formula)
    const int  o1i = tid + 256;
    const bool cp1 = (o1i < OIDX_N);
    const int  o1r = o1i / NW4, o1c = o1i - o1r * NW4;

    const int sw0 = s0r * DW_W + s0c * 4;   // LDS float offsets (staging)
    const int sw1 = s1r * DW_W + s1c * 4;

    // fetch raw chunk data into regs (zeros outside the plane)
    auto fetch = [&](int chunk, float4& a, float4& b) {
        const int plane = p0 + (chunk >> 1);
        const int half  = chunk & 1;
        const float* xp = x + (size_t)plane * DW_HW;
        const int g0 = half * 28 - 1 + s0r;        // global row of staging slot 0
        a.x = a.y = a.z = a.w = 0.0f;
        if (g0 >= 0 && g0 < DW_H) a = *(const float4*)(xp + g0 * DW_W + s0c * 4);
        b.x = b.y = b.z = b.w = 0.0f;
        if (st1) {
            const int g1 = half * 28 - 1 + s1r;
            if (g1 >= 0 && g1 < DW_H) b = *(const float4*)(xp + g1 * DW_W + s1c * 4);
        }
    };
    // quantize + write staged regs into an LDS buffer
    auto commit = [&](float* buf, const float4& a, const float4& b) {
        *(float4*)(buf + sw0) = qfix4(a);
        if (st1) *(float4*)(buf + sw1) = qfix4(b);
    };

    // ---- prologue: stage chunk 0 ----
    {
        float4 a, b;
        fetch(0, a, b);
        commit(s[0], a, b);
    }
    __syncthreads();

    for (int ch = 0; ch < CHUNKS; ++ch) {
        const int plane = p0 + (ch >> 1);
        const int half  = ch & 1;
        const bool more = (ch + 1 < CHUNKS);

        // ---- issue next chunk's global loads EARLY (in flight during compute) ----
        float4 na, nb;
        if (more) fetch(ch + 1, na, nb);

        // ---- per-channel quantized weights + bias ----
        const int c = plane % DW_C;
        float ww[9], bqv;
        if (PRE) {
            const float* wp = wsq + c * 9;
#pragma unroll
            for (int t = 0; t < 9; ++t) ww[t] = wp[t];
            bqv = wsb[c];
        } else {
            const float* wp = wgt + c * 9;
#pragma unroll
            for (int t = 0; t < 9; ++t) {
                float wv = wp[t];
                float aw = fabsf(wv);
                float cw = fminf(fmaxf(aw, 6.103515625e-05f), 1.0f);
                float q  = exp2f(rintf(log2f(cw)));
                ww[t] = (wv > 0.0f) ? q : ((wv < 0.0f) ? -q : 0.0f);
            }
            bqv = qfix(bias[c]);
        }

        // ---- compute 28 output rows from LDS buffer s[ch&1] ----
        const float* buf = s[ch & 1];
        float* op = out + (size_t)plane * DW_HW + half * 28 * DW_W;

#define ROWFMA(RP, HL, HR, W0, W1, W2) {                               \
            const float* rp_ = (RP);                                   \
            float4 m_ = *(const float4*)rp_;                           \
            float L_ = (HL) ? rp_[-1] : 0.0f;                          \
            float R_ = (HR) ? rp_[4]  : 0.0f;                          \
            a0 = fmaf(L_,   W0, fmaf(m_.x, W1, fmaf(m_.y, W2, a0)));  \
            a1 = fmaf(m_.x, W0, fmaf(m_.y, W1, fmaf(m_.z, W2, a1)));  \
            a2 = fmaf(m_.y, W0, fmaf(m_.z, W1, fmaf(m_.w, W2, a2)));  \
            a3 = fmaf(m_.z, W0, fmaf(m_.w, W1, fmaf(R_,   W2, a3))); }

#define CGROUP(OR, OC, EN) if (EN) {                                   \
            float a0 = bqv, a1 = bqv, a2 = bqv, a3 = bqv;              \
            const bool hl_ = ((OC) > 0), hr_ = ((OC) < NW4 - 1);       \
            const float* base = buf + (OR) * DW_W + (OC) * 4;          \
            ROWFMA(base,            hl_, hr_, ww[0], ww[1], ww[2]);    \
            ROWFMA(base + DW_W,     hl_, hr_, ww[3], ww[4], ww[5]);    \
            ROWFMA(base + 2 * DW_W, hl_, hr_, ww[6], ww[7], ww[8]);    \
            float4 ov_; ov_.x = a0; ov_.y = a1; ov_.z = a2; ov_.w = a3;\
            *(float4*)(op + (OR) * DW_W + (OC) * 4) = ov_; }

        // output row r (0..27) uses buffer rows r..r+2 (halos pre-staged as zeros)
        CGROUP(s0r, s0c, true)
        CGROUP(o1r, o1c, cp1)

#undef CGROUP
#undef ROWFMA

        // ---- quantize + write next chunk to the other buffer ----
        if (more) commit((float*)s[(ch + 1) & 1], na, nb);
        __syncthreads();
    }
}

extern "C" void kernel_launch(void* const* d_in, const int* in_sizes, int n_in,
                              void* d_out, int out_size, void* d_ws, size_t ws_size,
                              hipStream_t stream) {
    const float* x = (const float*)d_in[0];
    const float* w = (const float*)d_in[1];
    const float* b = (const float*)d_in[2];
    float* out = (float*)d_out;

    int planes  = in_sizes[0] / DW_HW;   // 32*384 = 12288
    int nblocks = planes / PPB;          // 2048 = 8 blocks/CU exact

    size_t need = (size_t)(DW_C * 9 + DW_C) * sizeof(float);
    if (d_ws && ws_size >= need) {
        float* wq = (float*)d_ws;
        float* bq = wq + DW_C * 9;
        quant_wb<<<(DW_C * 9 + 255) / 256, 256, 0, stream>>>(w, b, wq, bq);
        peg_shift_pipe<true><<<nblocks, 256, 0, stream>>>(x, w, b, out, wq, bq);
    } else {
        peg_shift_pipe<false><<<nblocks, 256, 0, stream>>>(x, w, b, out, nullptr, nullptr);
    }
}

// Round 9
// 270.894 us; speedup vs baseline: 1.7035x; 1.0394x over previous
//
#include <hip/hip_runtime.h>

// PEG_Shift: depthwise 3x3 conv (stride 1, pad 1, groups=C), power-of-two weights,
// 16-bit fixed-point activations/bias. x: (32,384,56,56) f32.
//
// v8: v1 shell (1 plane/block, 12288 blocks, single barrier) + LDS-pipe fix.
//   Evidence: v7 cut VALU 40->19% yet time rose 96->101us with conflicts 5.3->14.2M
//   -> LDS pipe (reads + conflicts) is the critical path, not latency, not VALU.
//   - register-window compute: thread owns 4-wide x 4-row strip, walks down;
//     1 LDS row-read per output row (3x fewer reads than v7)
//   - halo rows AND halo columns pre-zeroed -> branch-free 3x3 inner loop
//   - stride 68 dwords + per-row XOR swizzle (d ^= ((r>>2)&3)<<3) -> the strip
//     pattern's g/g+2 bank collisions separated; residual aliasing is 2-way (free)
//   - weights/bias pre-quantized into d_ws (v7, kept)

#define DW_C   384
#define DW_H   56
#define DW_W   56
#define DW_HW  3136
#define NW4    14
#define ROWS_L 58                    // 56 data rows + top/bottom zero halo rows
#define STRIDE 68                    // dwords/row: L halo @3, data @4..59, R halo @60
#define LDS_DW (ROWS_L * STRIDE)     // 3944 dwords = 15.8 KB

__device__ __forceinline__ float qfix(float v) {
    // floor(v * 2^16) * 2^-16, clip [-2^15, 2^15-1] — exact in fp32
    v = floorf(v * 65536.0f) * (1.0f / 65536.0f);
    return fminf(fmaxf(v, -32768.0f), 32767.0f);   // v_med3_f32
}

__device__ __forceinline__ float4 qfix4(float4 v) {
    v.x = qfix(v.x); v.y = qfix(v.y); v.z = qfix(v.z); v.w = qfix(v.w);
    return v;
}

// physical dword index for (LDS row r, logical dword-in-row d).
// XOR of bits 3..4 keyed by (r>>2): rows of strip g and strip g+2 (which share
// bank classes at stride 68) get different 8-dword rotations; 16B blocks preserved.
__device__ __forceinline__ int swz(int r, int d) {
    return r * STRIDE + (d ^ (((r >> 2) & 3) << 3));
}

struct RowW { float l, a, b, cN, d, r; };

// ---- pre-kernel: quantize 3456 weights (power of two) + 384 biases into d_ws ----
__global__ __launch_bounds__(256) void quant_wb(
    const float* __restrict__ wgt, const float* __restrict__ bias,
    float* __restrict__ wq, float* __restrict__ bq)
{
    int i = blockIdx.x * 256 + threadIdx.x;
    if (i < DW_C * 9) {
        float wv = wgt[i];
        float aw = fabsf(wv);
        float cw = fminf(fmaxf(aw, 6.103515625e-05f /*2^-14*/), 1.0f);
        float q  = exp2f(rintf(log2f(cw)));        // rint = round-half-even (jnp.round)
        wq[i] = (wv > 0.0f) ? q : ((wv < 0.0f) ? -q : 0.0f);
    }
    if (i < DW_C) bq[i] = qfix(bias[i]);
}

template<bool PRE>
__global__ __launch_bounds__(256) void peg_shift_v8(
    const float* __restrict__ x, const float* __restrict__ wgt,
    const float* __restrict__ bias, float* __restrict__ out,
    const float* __restrict__ wsq, const float* __restrict__ wsb)
{
    __shared__ float sm[LDS_DW];

    const int tid   = threadIdx.x;
    const int plane = blockIdx.x;
    const int ch    = plane % DW_C;

    // ---- zero halo rows (0, 57: all 68 dwords) and halo columns (rows 1..56) ----
    if (tid < 2 * STRIDE) {
        int r = (tid < STRIDE) ? 0 : (ROWS_L - 1);
        sm[r * STRIDE + (tid % STRIDE)] = 0.0f;     // whole row: swizzle irrelevant
    }
    {
        int i = tid;                                 // 112 halo-column zeros
        if (i < 112) {
            int r = 1 + (i >> 1);
            int d = (i & 1) ? 60 : 3;
            sm[swz(r, d)] = 0.0f;
        }
    }

    // ---- stage plane, quantizing on the way in (784 float4 slots) ----
    {
        const float4* x4 = (const float4*)(x + (size_t)plane * DW_HW);
#pragma unroll
        for (int j = 0; j < 4; ++j) {
            int s_ = tid + j * 256;
            if (s_ < 784) {                          // j=3 active only for tid<16
                float4 v = x4[s_];
                int r  = 1 + s_ / NW4;
                int cc = s_ - (s_ / NW4) * NW4;
                *(float4*)&sm[swz(r, 4 + 4 * cc)] = qfix4(v);
            }
        }
    }

    // ---- per-channel quantized weights + bias (uniform per block) ----
    float ww[9], bqv;
    if (PRE) {
        const float* wp = wsq + ch * 9;
#pragma unroll
        for (int t = 0; t < 9; ++t) ww[t] = wp[t];
        bqv = wsb[ch];
    } else {
        const float* wp = wgt + ch * 9;
#pragma unroll
        for (int t = 0; t < 9; ++t) {
            float wv = wp[t];
            float aw = fabsf(wv);
            float cw = fminf(fmaxf(aw, 6.103515625e-05f), 1.0f);
            float q  = exp2f(rintf(log2f(cw)));
            ww[t] = (wv > 0.0f) ? q : ((wv < 0.0f) ? -q : 0.0f);
        }
        bqv = qfix(bias[ch]);
    }

    __syncthreads();

    // ---- compute: 196 threads, each a 4-wide x 4-row strip (g=row group, cc=col) ----
    if (tid < 196) {
        const int g  = tid / NW4;        // 0..13   (c-fastest lane order)
        const int cc = tid - g * NW4;    // 0..13
        const int dl = 3 + 4 * cc, dm = 4 + 4 * cc, dr = 8 + 4 * cc;

        auto ldrow = [&](int rl) -> RowW {
            RowW R;
            R.l = sm[swz(rl, dl)];
            float4 m = *(const float4*)&sm[swz(rl, dm)];
            R.a = m.x; R.b = m.y; R.cN = m.z; R.d = m.w;
            R.r = sm[swz(rl, dr)];
            return R;
        };

        // output rows 4g..4g+3 use LDS rows 4g..4g+5 (LDS row = input row + 1)
        RowW A = ldrow(4 * g);
        RowW B = ldrow(4 * g + 1);
        RowW C = ldrow(4 * g + 2);

        float* op = out + (size_t)plane * DW_HW + (4 * g) * DW_W + 4 * cc;

#define ROWF(RW, W0, W1, W2)                                            \
        o0 = fmaf(RW.l,  W0, fmaf(RW.a,  W1, fmaf(RW.b,  W2, o0)));     \
        o1 = fmaf(RW.a,  W0, fmaf(RW.b,  W1, fmaf(RW.cN, W2, o1)));     \
        o2 = fmaf(RW.b,  W0, fmaf(RW.cN, W1, fmaf(RW.d,  W2, o2)));     \
        o3 = fmaf(RW.cN, W0, fmaf(RW.d,  W1, fmaf(RW.r,  W2, o3)));

#pragma unroll
        for (int i = 0; i < 4; ++i) {
            float o0 = bqv, o1 = bqv, o2 = bqv, o3 = bqv;
            ROWF(A, ww[0], ww[1], ww[2])
            ROWF(B, ww[3], ww[4], ww[5])
            ROWF(C, ww[6], ww[7], ww[8])
            float4 ov; ov.x = o0; ov.y = o1; ov.z = o2; ov.w = o3;
            *(float4*)op = ov;
            op += DW_W;
            if (i < 3) {                  // slide window down one row
                A = B; B = C;
                C = ldrow(4 * g + 3 + i);
            }
        }
#undef ROWF
    }
}

extern "C" void kernel_launch(void* const* d_in, const int* in_sizes, int n_in,
                              void* d_out, int out_size, void* d_ws, size_t ws_size,
                              hipStream_t stream) {
    const float* x = (const float*)d_in[0];
    const float* w = (const float*)d_in[1];
    const float* b = (const float*)d_in[2];
    float* out = (float*)d_out;

    int planes = in_sizes[0] / DW_HW;   // 32*384 = 12288 blocks, 1 plane each

    size_t need = (size_t)(DW_C * 9 + DW_C) * sizeof(float);
    if (d_ws && ws_size >= need) {
        float* wq = (float*)d_ws;
        float* bq = wq + DW_C * 9;
        quant_wb<<<(DW_C * 9 + 255) / 256, 256, 0, stream>>>(w, b, wq, bq);
        peg_shift_v8<true><<<planes, 256, 0, stream>>>(x, w, b, out, wq, bq);
    } else {
        peg_shift_v8<false><<<planes, 256, 0, stream>>>(x, w, b, out, nullptr, nullptr);
    }
}